// Round 5
// baseline (487.196 us; speedup 1.0000x reference)
//
#include <hip/hip_runtime.h>
#include <hip/hip_bf16.h>

// LDS.sampleX: x[t] = A x[t-1] + Q e[t], parallelized via contraction warm-up.
// 20000 chunks x T=50 steps, W=30 warmup. 16 chunks per wave; per step:
// X_new(64x16) = A*X + Q*E via 16x16x32 bf16 MFMA.
//
// Round-5: DEPTH-5 software-pipelined E loads. Round-4 was depth-1 lock-step:
// each wave had one 8KB batch in flight, fully drained before the next batch
// (counters: all waves resident, 2.4 TB/s, 4.8us/batch) -> latency pipeline
// never filled. Now 5 steps x 4 dwordx4 are continuously in flight per wave
// (static named buffers E0..E4 - no runtime indexing, no scratch), converted
// 5 steps after issue. Single uniform loop (warm vs output handled by cheap
// uniform predicates; chunk-0 warm-head zeroing via per-lane select in the
// convert). LDS holds only state (bf16 hi+lo compensated, ~5KB).

using bf16x8 = __attribute__((ext_vector_type(8))) short;
using s16x4  = __attribute__((ext_vector_type(4))) short;
using f32x4  = __attribute__((ext_vector_type(4))) float;

#define N_STEPS   1000000
#define XD        64
#define T_CHUNK   50
#define WARM      30
#define STOT      (WARM + T_CHUNK)      /* 80 */
#define DEPTH     5                     /* E-load prefetch distance (steps) */
#define N_CHUNKS  (N_STEPS / T_CHUNK)   /* 20000 */
#define N_BLOCKS  (N_CHUNKS / 16)       /* 1250 */
#define PAD       66                    /* state LDS row stride (bf16 elems) */

__device__ __forceinline__ short f2bf_rne(float f) {
    unsigned u = __builtin_bit_cast(unsigned, f);
    u += 0x7FFFu + ((u >> 16) & 1u);
    return (short)(u >> 16);
}
__device__ __forceinline__ float bf2f(short s) {
    return __builtin_bit_cast(float, ((unsigned)(unsigned short)s) << 16);
}
__device__ __forceinline__ short f2bf_hw(float f) {   // HW RNE convert
    return __builtin_bit_cast(short, __float2bfloat16(f));
}

__global__ __launch_bounds__(64, 2) void lds_scan_kernel(
    const float* __restrict__ eps,   // [N_STEPS, 64]
    const float* __restrict__ A,     // [64, 64] row-major
    const float* __restrict__ Q,     // [64, 64]
    const float* __restrict__ Q0,    // [64, 64]
    const float* __restrict__ x0,    // [64]
    float* __restrict__ out)         // [N_STEPS, 64]
{
    __shared__ short Xh[16 * PAD];   // state hi, [chunk][dim] bf16
    __shared__ short Xl[16 * PAD];   // state lo (residual)
    __shared__ float corr[XD];       // chunk-0 t=0 correction: x0 + (Q0-Q) e0
    __shared__ float e0s[XD];

    const int lane = threadIdx.x;    // 0..63 (one wave per block)
    const int cl   = lane & 15;      // chunk column (n in MFMA B and C/D layouts)
    const int g    = lane >> 4;      // quad index

    for (int i = lane; i < 16 * PAD; i += 64) { Xh[i] = 0; Xl[i] = 0; }

    if (blockIdx.x == 0) e0s[lane] = eps[lane];
    __syncthreads();
    if (blockIdx.x == 0) {
        float c = x0[lane];
        #pragma unroll 8
        for (int j = 0; j < XD; ++j)
            c += (Q0[lane * XD + j] - Q[lane * XD + j]) * e0s[j];
        corr[lane] = c;
    }
    __syncthreads();

    // Constant A/Q fragments, MFMA A-operand layout:
    // lane holds M[mt*16 + (lane&15)][ks*32 + (lane>>4)*8 + j], j=0..7
    bf16x8 Af[4][2], Qf[4][2];
    #pragma unroll
    for (int mt = 0; mt < 4; ++mt) {
        #pragma unroll
        for (int ks = 0; ks < 2; ++ks) {
            const float* ap = A + (mt * 16 + cl) * XD + ks * 32 + g * 8;
            const float* qp = Q + (mt * 16 + cl) * XD + ks * 32 + g * 8;
            bf16x8 af, qf;
            #pragma unroll
            for (int j = 0; j < 8; ++j) { af[j] = f2bf_rne(ap[j]); qf[j] = f2bf_rne(qp[j]); }
            Af[mt][ks] = af; Qf[mt][ks] = qf;
        }
    }

    const int chunk = blockIdx.x * 16 + cl;          // this lane's chunk column
    const int tb    = chunk * T_CHUNK - WARM;        // lane's step->row offset
    float* po = out + (long)chunk * T_CHUNK * XD;    // output base for this chunk

    // E pipeline buffers: one step each, static names (no runtime indexing).
    struct EB { f32x4 a, b, c, d; };
    EB E0, E1, E2, E3, E4;

    // Issue one step's B-fragment loads direct global->VGPR.
    // 4 x dwordx4; the 4 instrs together consume each touched row fully.
    #define LOADS(BUF, S) {                                                \
        const int t_  = tb + (S);                                          \
        const int tc_ = t_ < 0 ? 0 : t_;        /* chunk-0 warm head */    \
        const float* p_ = eps + (long)tc_ * XD + g * 8;                    \
        BUF.a = *(const f32x4*)(p_);                                       \
        BUF.b = *(const f32x4*)(p_ + 4);                                   \
        BUF.c = *(const f32x4*)(p_ + 32);                                  \
        BUF.d = *(const f32x4*)(p_ + 36);                                  \
        asm volatile("" ::: "memory");          /* pin issue position */   \
    }

    // Convert buffer -> bf16 B-fragments, zeroing chunk-0 warm-head rows.
    #define CONVM(BUF, S, ef0, ef1) {                                      \
        const bool z_ = (tb + (S)) < 0;                                    \
        _Pragma("unroll")                                                  \
        for (int j = 0; j < 4; ++j) {                                      \
            ef0[j]     = f2bf_hw(z_ ? 0.f : BUF.a[j]);                     \
            ef0[4 + j] = f2bf_hw(z_ ? 0.f : BUF.b[j]);                     \
            ef1[j]     = f2bf_hw(z_ ? 0.f : BUF.c[j]);                     \
            ef1[4 + j] = f2bf_hw(z_ ? 0.f : BUF.d[j]);                     \
        }                                                                  \
    }

    auto step = [&](bf16x8 ef0, bf16x8 ef1, int s, bool store_out, bool inject) {
        // state fragments from LDS
        bf16x8 xh0 = *(const bf16x8*)&Xh[cl * PAD +  0 + g * 8];
        bf16x8 xh1 = *(const bf16x8*)&Xh[cl * PAD + 32 + g * 8];
        bf16x8 xl0 = *(const bf16x8*)&Xl[cl * PAD +  0 + g * 8];
        bf16x8 xl1 = *(const bf16x8*)&Xl[cl * PAD + 32 + g * 8];

        // X_new = A*(xh + xl) + Q*e; Q*e first (state-independent), two
        // parallel accumulator chains (state-dependent MFMA depth = 2).
        f32x4 acc[4];
        #pragma unroll
        for (int mt = 0; mt < 4; ++mt) {
            f32x4 a  = {0.f, 0.f, 0.f, 0.f};
            f32x4 a2 = {0.f, 0.f, 0.f, 0.f};
            a  = __builtin_amdgcn_mfma_f32_16x16x32_bf16(Qf[mt][0], ef0, a,  0, 0, 0);
            a2 = __builtin_amdgcn_mfma_f32_16x16x32_bf16(Qf[mt][1], ef1, a2, 0, 0, 0);
            a  = __builtin_amdgcn_mfma_f32_16x16x32_bf16(Af[mt][0], xh0, a,  0, 0, 0);
            a2 = __builtin_amdgcn_mfma_f32_16x16x32_bf16(Af[mt][1], xh1, a2, 0, 0, 0);
            a  = __builtin_amdgcn_mfma_f32_16x16x32_bf16(Af[mt][0], xl0, a,  0, 0, 0);
            a2 = __builtin_amdgcn_mfma_f32_16x16x32_bf16(Af[mt][1], xl1, a2, 0, 0, 0);
            acc[mt] = a + a2;
        }

        // chunk 0, t==0: inject x0 + (Q0 - Q) e0 so result = x0 + Q0 e0
        if (inject && blockIdx.x == 0 && cl == 0) {
            #pragma unroll
            for (int mt = 0; mt < 4; ++mt)
                #pragma unroll
                for (int r = 0; r < 4; ++r)
                    acc[mt][r] += corr[mt * 16 + g * 4 + r];
        }

        // write back compensated state (C/D layout: lane=chunk cl, dims mt*16+g*4+r).
        // Truncation split: pair precision equals RNE split; hi is 1 VALU op.
        #pragma unroll
        for (int mt = 0; mt < 4; ++mt) {
            s16x4 hi, lo;
            #pragma unroll
            for (int r = 0; r < 4; ++r) {
                const float v = acc[mt][r];
                const short h = (short)(__builtin_bit_cast(unsigned, v) >> 16);
                hi[r] = h;
                const float rem = v - bf2f(h);
                lo[r] = (short)(__builtin_bit_cast(unsigned, rem) >> 16);
            }
            *(s16x4*)&Xh[cl * PAD + mt * 16 + g * 4] = hi;
            *(s16x4*)&Xl[cl * PAD + mt * 16 + g * 4] = lo;
        }

        if (store_out) {
            float* op = po + (long)(s - WARM) * XD;
            #pragma unroll
            for (int mt = 0; mt < 4; ++mt)
                *(f32x4*)(op + mt * 16 + g * 4) = acc[mt];
        }
    };
    // ------------------------------------------------------------------------

    // prologue: fill the pipeline (steps 0..4 in flight)
    LOADS(E0, 0) LOADS(E1, 1) LOADS(E2, 2) LOADS(E3, 3) LOADS(E4, 4)

    // steady state: consume step s, immediately reissue its buffer for s+DEPTH.
    // 15 iterations cover steps 0..74; loads reach step 79.
    for (int i = 0; i < STOT - DEPTH; i += DEPTH) {
        bf16x8 f0, f1;
        CONVM(E0, i + 0, f0, f1); step(f0, f1, i + 0, (i + 0) >= WARM, (i + 0) == WARM); LOADS(E0, i + DEPTH + 0)
        CONVM(E1, i + 1, f0, f1); step(f0, f1, i + 1, (i + 1) >= WARM, false);           LOADS(E1, i + DEPTH + 1)
        CONVM(E2, i + 2, f0, f1); step(f0, f1, i + 2, (i + 2) >= WARM, false);           LOADS(E2, i + DEPTH + 2)
        CONVM(E3, i + 3, f0, f1); step(f0, f1, i + 3, (i + 3) >= WARM, false);           LOADS(E3, i + DEPTH + 3)
        CONVM(E4, i + 4, f0, f1); step(f0, f1, i + 4, (i + 4) >= WARM, false);           LOADS(E4, i + DEPTH + 4)
    }
    // epilogue: steps 75..79 (all output steps; inject happened at i=30)
    {
        const int i = STOT - DEPTH;
        bf16x8 f0, f1;
        CONVM(E0, i + 0, f0, f1); step(f0, f1, i + 0, true, false);
        CONVM(E1, i + 1, f0, f1); step(f0, f1, i + 1, true, false);
        CONVM(E2, i + 2, f0, f1); step(f0, f1, i + 2, true, false);
        CONVM(E3, i + 3, f0, f1); step(f0, f1, i + 3, true, false);
        CONVM(E4, i + 4, f0, f1); step(f0, f1, i + 4, true, false);
    }
}

extern "C" void kernel_launch(void* const* d_in, const int* in_sizes, int n_in,
                              void* d_out, int out_size, void* d_ws, size_t ws_size,
                              hipStream_t stream) {
    const float* eps = (const float*)d_in[0];   // norm_samp [1e6, 64]
    const float* A   = (const float*)d_in[1];   // [64,64]
    const float* Q   = (const float*)d_in[2];   // QChol [64,64]
    const float* Q0  = (const float*)d_in[3];   // Q0Chol [64,64]
    const float* x0  = (const float*)d_in[4];   // [64]
    float* out = (float*)d_out;

    lds_scan_kernel<<<N_BLOCKS, 64, 0, stream>>>(eps, A, Q, Q0, x0, out);
}